// Round 1
// baseline (1483.632 us; speedup 1.0000x reference)
//
#include <hip/hip_runtime.h>
#include <stdint.h>

#define NSITES 256
#define NHID   64
#define BATCH  8192

// ---------------- threefry2x32 (exact JAX semantics) ----------------
__device__ __forceinline__ uint32_t rotl32(uint32_t v, int d) {
  return (v << d) | (v >> (32 - d));
}

__device__ __forceinline__ void tf2x32(uint32_t k0, uint32_t k1,
                                       uint32_t x0, uint32_t x1,
                                       uint32_t& o0, uint32_t& o1) {
  uint32_t ks2 = k0 ^ k1 ^ 0x1BD11BDAu;
  x0 += k0; x1 += k1;
#define TFR4(a,b,c,d) \
  x0 += x1; x1 = rotl32(x1,a); x1 ^= x0; \
  x0 += x1; x1 = rotl32(x1,b); x1 ^= x0; \
  x0 += x1; x1 = rotl32(x1,c); x1 ^= x0; \
  x0 += x1; x1 = rotl32(x1,d); x1 ^= x0;
  TFR4(13,15,26,6)   x0 += k1;  x1 += ks2 + 1u;
  TFR4(17,29,16,24)  x0 += ks2; x1 += k0  + 2u;
  TFR4(13,15,26,6)   x0 += k0;  x1 += k1  + 3u;
  TFR4(17,29,16,24)  x0 += k1;  x1 += ks2 + 4u;
  TFR4(13,15,26,6)   x0 += ks2; x1 += k0  + 5u;
#undef TFR4
  o0 = x0; o1 = x1;
}

// gumbel from raw 32 bits, exactly as jax.random.gumbel/uniform does it
__device__ __forceinline__ float gumb_from_bits(uint32_t bits) {
  float f = __uint_as_float((bits >> 9) | 0x3f800000u) - 1.0f;
  float u = (f == 0.0f) ? 1.17549435e-38f : f;   // == max(tiny, f*1.0f+tiny)
  return -logf(-logf(u));
}

// partitionable-threefry 32-bit random bits for flat element index e,
// under key (k0,k1):  counter = (hi,lo) = (0,e);  bits = out0 ^ out1
__device__ __forceinline__ uint32_t rbits32(uint32_t k0, uint32_t k1, uint32_t e) {
  uint32_t a, b;
  tf2x32(k0, k1, 0u, e, a, b);
  return a ^ b;
}

// ---------------- gumbel precompute kernel ----------------
// g[t*BATCH + b] = (gumbel for class 0, gumbel for class 1) at step t, sample b
__global__ void gumbel_precompute(float2* __restrict__ g) {
  int idx = blockIdx.x * blockDim.x + threadIdx.x;   // 0 .. 256*8192-1
  if (idx >= NSITES * BATCH) return;
  int t = idx >> 13;            // / 8192
  int b = idx & (BATCH - 1);
  // keys[t] = threefry2x32((0,1234), (0,t))   [fold-like split, partitionable]
  uint32_t kt0, kt1;
  tf2x32(0u, 1234u, 0u, (uint32_t)t, kt0, kt1);
  uint32_t r0 = rbits32(kt0, kt1, (uint32_t)(2 * b));
  uint32_t r1 = rbits32(kt0, kt1, (uint32_t)(2 * b + 1));
  g[idx] = make_float2(gumb_from_bits(r0), gumb_from_bits(r1));
}

// XLA's logistic_expander form: 0.5 + 0.5*tanh(0.5*x)
__device__ __forceinline__ float sigmoid_xla(float x) {
  return 0.5f + 0.5f * tanhf(0.5f * x);
}

// ---------------- main autoregressive kernel ----------------
// One wave (64 lanes) per sample. Lane l owns hidden unit l and the three
// Wh columns (z,r,h) for that unit in VGPRs. Broadcast of h across lanes is
// done with v_readlane (SGPR operand into the FMA).
template <bool PRE>
__global__ __launch_bounds__(256, 2) void rnn_sample(
    const float* __restrict__ Wi,   // [2][192]
    const float* __restrict__ Wh,   // [64][192]
    const float* __restrict__ bb,   // [2][192]
    const float* __restrict__ Wd,   // [64][2]
    const float* __restrict__ bd,   // [2]
    const float2* __restrict__ g,   // [256][8192] gumbels (if PRE)
    float* __restrict__ out_s,      // [8192][256]
    float* __restrict__ out_lp)     // [8192]
{
  const int lane = threadIdx.x & 63;
  const int wid  = threadIdx.x >> 6;
  const int b    = __builtin_amdgcn_readfirstlane(blockIdx.x * 4 + wid);

  // ---- load per-lane weights into registers ----
  float wz[NHID], wr[NHID], wh[NHID];
#pragma unroll
  for (int j = 0; j < NHID; ++j) {
    wz[j] = Wh[j * 192 + lane];
    wr[j] = Wh[j * 192 + 64 + lane];
    wh[j] = Wh[j * 192 + 128 + lane];
  }
  const float b1z = bb[192 + lane];
  const float b1r = bb[192 + 64 + lane];
  const float b1h = bb[192 + 128 + lane];
  // mx table: row0 = b0 (zero input), row1 = Wi[0]+b0, row2 = Wi[1]+b0
  const float m0z = bb[lane],        m0r = bb[64 + lane],        m0h = bb[128 + lane];
  const float m1z = Wi[lane] + m0z,  m1r = Wi[64 + lane] + m0r,  m1h = Wi[128 + lane] + m0h;
  const float m2z = Wi[192 + lane] + m0z, m2r = Wi[192 + 64 + lane] + m0r,
              m2h = Wi[192 + 128 + lane] + m0h;
  const float wd0 = Wd[lane * 2 + 0], wd1 = Wd[lane * 2 + 1];
  const float bd0 = bd[0], bd1 = bd[1];

  float h = 0.0f;
  float lpsum = 0.0f;
  int sprev = -1;

  float2 gc;
  if (PRE) gc = g[b];   // step 0

  for (int t = 0; t < NSITES; ++t) {
    float2 gn = gc;
    if (PRE && t < NSITES - 1) gn = g[(t + 1) * BATCH + b];

    float g0, g1;
    if (PRE) { g0 = gc.x; g1 = gc.y; }
    else {
      uint32_t kt0, kt1;
      tf2x32(0u, 1234u, 0u, (uint32_t)t, kt0, kt1);
      g0 = gumb_from_bits(rbits32(kt0, kt1, (uint32_t)(2 * b)));
      g1 = gumb_from_bits(rbits32(kt0, kt1, (uint32_t)(2 * b + 1)));
    }

    // mx select by previous sample (one-hot input @ Wi + b0, exact)
    const float xz = (sprev < 0) ? m0z : ((sprev == 0) ? m1z : m2z);
    const float xr = (sprev < 0) ? m0r : ((sprev == 0) ? m1r : m2r);
    const float xh = (sprev < 0) ? m0h : ((sprev == 0) ? m1h : m2h);

    // mh = h @ Wh  (h broadcast via readlane, fma chain per gate)
    float az = 0.0f, ar = 0.0f, ah = 0.0f;
#pragma unroll
    for (int j = 0; j < NHID; ++j) {
      const float hj = __int_as_float(__builtin_amdgcn_readlane(__float_as_int(h), j));
      az = fmaf(hj, wz[j], az);
      ar = fmaf(hj, wr[j], ar);
      ah = fmaf(hj, wh[j], ah);
    }
    const float rz = az + b1z;
    const float rr = ar + b1r;
    const float rh = ah + b1h;

    const float zg = sigmoid_xla(xz + rz);
    const float rg = sigmoid_xla(xr + rr);
    const float hg = tanhf(xh + rg * rh);
    h = zg * h + (1.0f - zg) * hg;

    // logits = h @ Wd + bd  (butterfly reduce over the wave)
    float p0 = h * wd0, p1 = h * wd1;
#pragma unroll
    for (int off = 32; off > 0; off >>= 1) {
      p0 += __shfl_xor(p0, off, 64);
      p1 += __shfl_xor(p1, off, 64);
    }
    const float l0 = p0 + bd0, l1 = p1 + bd1;

    // log_softmax (shift form, same as jax.nn.log_softmax)
    const float mmax = fmaxf(l0, l1);
    const float sh0 = l0 - mmax, sh1 = l1 - mmax;
    const float lse = logf(expf(sh0) + expf(sh1));

    // categorical = argmax(logits + gumbel), ties -> 0
    const float v0 = l0 + g0, v1 = l1 + g1;
    const int s = (v1 > v0) ? 1 : 0;

    lpsum += (s ? sh1 : sh0) - lse;
    if (lane == 0) out_s[(size_t)b * NSITES + t] = (float)s;
    sprev = s;
    gc = gn;
  }

  if (lane == 0) out_lp[b] = 0.5f * lpsum;
}

extern "C" void kernel_launch(void* const* d_in, const int* in_sizes, int n_in,
                              void* d_out, int out_size, void* d_ws, size_t ws_size,
                              hipStream_t stream) {
  // inputs: [0]=numsamples(int,1) [1]=Wi[2,192] [2]=Wh[64,192] [3]=b[2,192]
  //         [4]=Wd[64,2] [5]=bd[2]
  const float* Wi = (const float*)d_in[1];
  const float* Wh = (const float*)d_in[2];
  const float* bb = (const float*)d_in[3];
  const float* Wd = (const float*)d_in[4];
  const float* bd = (const float*)d_in[5];

  float* out   = (float*)d_out;
  float* out_s = out;                          // [8192][256]
  float* out_lp = out + (size_t)BATCH * NSITES; // [8192]

  const size_t gbytes = (size_t)NSITES * BATCH * sizeof(float2);
  if (ws_size >= gbytes) {
    float2* g = (float2*)d_ws;
    gumbel_precompute<<<(NSITES * BATCH) / 256, 256, 0, stream>>>(g);
    rnn_sample<true><<<BATCH / 4, 256, 0, stream>>>(Wi, Wh, bb, Wd, bd, g, out_s, out_lp);
  } else {
    rnn_sample<false><<<BATCH / 4, 256, 0, stream>>>(Wi, Wh, bb, Wd, bd, nullptr, out_s, out_lp);
  }
}